// Round 7
// baseline (1196.372 us; speedup 1.0000x reference)
//
#include <hip/hip_runtime.h>
#include <hip/hip_bf16.h>
#include <math.h>

// Problem constants
#define Bq   128
#define Tq   512
#define Iq   300   // input dim
#define Hq   150   // hidden per dir
#define G3   450   // 3*H
#define Kq   6
#define Cq   300
#define D2   300   // 2*H
#define THq  20
#define CLSq 5

typedef __attribute__((ext_vector_type(8))) short short8;     // 8 bf16 (4 VGPR) MFMA A/B frag
typedef __attribute__((ext_vector_type(4))) float floatx4;    // MFMA C/D frag

// ---------------------------------------------------------------------------
// Kernel 0: fp32 -> bf16 cast (RNE). n4 = n/4.
// ---------------------------------------------------------------------------
__global__ __launch_bounds__(256) void cast_bf16_kernel(
    const float* __restrict__ in, __hip_bfloat16* __restrict__ out, int n4)
{
    const int i = blockIdx.x * 256 + threadIdx.x;
    if (i < n4) {
        float4 v = *(const float4*)(in + 4 * (size_t)i);
        out[4 * (size_t)i + 0] = __float2bfloat16(v.x);
        out[4 * (size_t)i + 1] = __float2bfloat16(v.y);
        out[4 * (size_t)i + 2] = __float2bfloat16(v.z);
        out[4 * (size_t)i + 3] = __float2bfloat16(v.w);
    }
}

// ---------------------------------------------------------------------------
// Kernel 1: gi GEMM via bf16 MFMA 16x16x32 (verified layouts, R6-proven).
// ---------------------------------------------------------------------------
#define LB 40

__global__ __launch_bounds__(256) void gi_gemm_mfma(
    const __hip_bfloat16* __restrict__ xb,    // [B][T][300] bf16
    const __hip_bfloat16* __restrict__ Wbf,   // [2][450][300] bf16
    const float* __restrict__ bf_, const float* __restrict__ bb_,
    float* __restrict__ gic, int t0f, int t0b, int tcShift)
{
    const int dir = blockIdx.z;
    const unsigned short* W = (const unsigned short*)(Wbf + (size_t)dir * G3 * Iq);
    const unsigned short* X = (const unsigned short*)xb;
    const float* bias = dir ? bb_ : bf_;
    const int t0 = dir ? t0b : t0f;
    const int TCr = 1 << tcShift;
    float* outb = gic + (size_t)dir * Bq * TCr * G3;

    const int m0 = blockIdx.y * 128;
    const int n0 = blockIdx.x * 128;
    const int tid  = threadIdx.x;
    const int wv   = tid >> 6, lane = tid & 63;
    const int wm   = wv & 1,  wn   = wv >> 1;
    const int quad = lane >> 4, mr = lane & 15;

    __shared__ __align__(16) unsigned short Ab[128 * LB];
    __shared__ __align__(16) unsigned short Bb[128 * LB];

    floatx4 acc[4][4];
    #pragma unroll
    for (int i = 0; i < 4; ++i)
        #pragma unroll
        for (int j = 0; j < 4; ++j)
            acc[i][j] = (floatx4){0.f, 0.f, 0.f, 0.f};

    for (int k0 = 0; k0 < 320; k0 += 32) {
        __syncthreads();
        #pragma unroll
        for (int i = 0; i < 4; ++i) {
            const int g = tid + 256 * i;         // 0..1023
            const int row = g >> 3, kq = g & 7;  // 4-bf16 granule
            const int k = k0 + kq * 4;
            const int r = m0 + row;
            const int bb2 = r >> tcShift, lt = r & (TCr - 1);
            ushort4 av = make_ushort4(0, 0, 0, 0);
            if (k < Iq)
                av = *(const ushort4*)(X + ((size_t)bb2 * Tq + t0 + lt) * Iq + k);
            *(ushort4*)&Ab[row * LB + kq * 4] = av;
            const int n = n0 + row;
            ushort4 bv = make_ushort4(0, 0, 0, 0);
            if (n < G3 && k < Iq)
                bv = *(const ushort4*)(W + (size_t)n * Iq + k);
            *(ushort4*)&Bb[row * LB + kq * 4] = bv;
        }
        __syncthreads();

        short8 af[4], bfr[4];
        #pragma unroll
        for (int i = 0; i < 4; ++i)
            af[i] = *(const short8*)&Ab[(wm * 64 + i * 16 + mr) * LB + quad * 8];
        #pragma unroll
        for (int j = 0; j < 4; ++j)
            bfr[j] = *(const short8*)&Bb[(wn * 64 + j * 16 + mr) * LB + quad * 8];
        #pragma unroll
        for (int i = 0; i < 4; ++i)
            #pragma unroll
            for (int j = 0; j < 4; ++j)
                acc[i][j] = __builtin_amdgcn_mfma_f32_16x16x32_bf16(
                    af[i], bfr[j], acc[i][j], 0, 0, 0);
    }

    #pragma unroll
    for (int j = 0; j < 4; ++j) {
        const int gn = n0 + wn * 64 + j * 16 + mr;
        if (gn >= G3) continue;
        const float bv = bias[gn];
        #pragma unroll
        for (int i = 0; i < 4; ++i) {
            const int mbase = m0 + wm * 64 + i * 16 + quad * 4;
            #pragma unroll
            for (int rg = 0; rg < 4; ++rg)
                outb[(size_t)(mbase + rg) * G3 + gn] = acc[i][j][rg] + bv;
        }
    }
}

// ---------------------------------------------------------------------------
// Kernel 2: GRU recurrence, eighth-split rows.
// Thread t = (row-oct ro=t>>3, eighth p=t&7), t<456: owns Whh rows
// 8ro..8ro+7 restricted to h-cols [p*19, p*19+19) (p=7: 17 cols) = 152
// weight floats (proven non-spilling footprint). h lives in LDS in
// eighth-padded layout (chunk p at float offset p*20, 16B aligned; 8 chunk
// addresses hit disjoint bank quads -> conflict-free). Per-step LDS pipe:
// 5 ds_read_b128/lane (was 19 in R5/R6, 38 in R3) -> 40 instr/CU/step.
// Partials combined via __shfl_xor 1/2/4 within the oct group.
// ---------------------------------------------------------------------------
__global__ __launch_bounds__(512, 2) void gru_rec(
    const float* __restrict__ gic,     // [2][B][TCr][450]
    const float* __restrict__ Whh_f, const float* __restrict__ bhh_f,
    const float* __restrict__ Whh_b, const float* __restrict__ bhh_b,
    float* __restrict__ hstate,        // [2][B][150]
    float* __restrict__ seq,           // [B][T][300]
    int chunk, int tcShift)
{
    const int TCr = 1 << tcShift;
    const int bid = blockIdx.x;
    const int dir = bid & 1;
    const int b   = bid >> 1;
    const float* Whh = dir ? Whh_b : Whh_f;
    const float* bhh = dir ? bhh_b : bhh_f;
    const int tid = threadIdx.x;
    const int ro  = tid >> 3;          // row-oct (rows 8ro..8ro+7), valid < 57
    const int p   = tid & 7;           // h-eighth
    const bool gact = (tid < 456);     // gemv role
    const bool iact = (tid < 450);     // gi-stage role (thread t loads gi row t)

    __shared__ __align__(16) float stage[64 * 150];  // W-staging, then h history
    __shared__ __align__(16) float4 hbuf4[40];       // h eighth-padded: 8 x 20 floats
    __shared__ __align__(16) float gh_s[456];
    __shared__ float gi_s[456];
    float* hbuf = (float*)hbuf4;

    // weights: w[r][c] = Whh[8ro+r][p*19+c], c<19 (p=7: c<17), else 0
    float w[8][19];

    for (int c = 0; c < 8; ++c) {
        const int r0 = c * 64;
        const int nrows = (r0 + 64 <= G3) ? 64 : (G3 - r0);
        const int nel = nrows * 150;
        __syncthreads();
        for (int idx = tid * 4; idx < nel; idx += 512 * 4)
            *(float4*)&stage[idx] = *(const float4*)(Whh + (size_t)r0 * 150 + idx);
        __syncthreads();
        if (gact && (ro >> 3) == c) {
            const int rl = 8 * ro - r0;             // 0..56, multiple of 8
            const int cmax = (p == 7) ? 17 : 19;
            #pragma unroll
            for (int r = 0; r < 8; ++r) {
                const bool rv = (8 * ro + r < G3) && (rl + r < nrows);
                #pragma unroll
                for (int cc = 0; cc < 19; ++cc)
                    w[r][cc] = (rv && cc < cmax)
                             ? stage[(rl + r) * 150 + p * 19 + cc] : 0.f;
            }
        }
    }
    // bias (only p==0 lanes use it; guarded loads for rows >= 450)
    float bh[8];
    #pragma unroll
    for (int r = 0; r < 8; ++r)
        bh[r] = (gact && p == 0 && 8 * ro + r < G3) ? bhh[8 * ro + r] : 0.f;

    float* hs = hstate + (size_t)(dir * Bq + b) * Hq;
    if (tid < 160) {
        const int pp = tid / 20, off = tid % 20;
        const int j = pp * 19 + off;
        hbuf[tid] = (off < 19 && j < Hq && chunk > 0) ? hs[j] : 0.f;
    }
    __syncthreads();

    const float* gib = gic + (size_t)(dir * Bq + b) * TCr * G3;
    const int t0 = dir ? (Tq - TCr * (chunk + 1)) : (chunk * TCr);
    float* seqb = seq + (size_t)b * Tq * D2 + dir * Hq;

    int lt = dir ? (TCr - 1) : 0;
    float gval = iact ? gib[(size_t)lt * G3 + tid] : 0.f;

    for (int s = 0; s < TCr; ++s) {
        const int ltn = dir ? (TCr - 2 - s) : (s + 1);
        float gnext = 0.f;
        if (s + 1 < TCr && iact)
            gnext = gib[(size_t)ltn * G3 + tid];

        if (iact) gi_s[tid] = gval;

        if (gact) {
            // this lane's h-eighth: 5 float4 broadcast-group reads
            const float4 hv0 = hbuf4[p * 5 + 0];
            const float4 hv1 = hbuf4[p * 5 + 1];
            const float4 hv2 = hbuf4[p * 5 + 2];
            const float4 hv3 = hbuf4[p * 5 + 3];
            const float4 hv4 = hbuf4[p * 5 + 4];   // .w is pad (w[.][19] absent)
            float acc[8];
            #pragma unroll
            for (int r = 0; r < 8; ++r) {
                acc[r] = hv0.x * w[r][0]  + hv0.y * w[r][1]
                       + hv0.z * w[r][2]  + hv0.w * w[r][3]
                       + hv1.x * w[r][4]  + hv1.y * w[r][5]
                       + hv1.z * w[r][6]  + hv1.w * w[r][7]
                       + hv2.x * w[r][8]  + hv2.y * w[r][9]
                       + hv2.z * w[r][10] + hv2.w * w[r][11]
                       + hv3.x * w[r][12] + hv3.y * w[r][13]
                       + hv3.z * w[r][14] + hv3.w * w[r][15]
                       + hv4.x * w[r][16] + hv4.y * w[r][17]
                       + hv4.z * w[r][18];
            }
            // combine the 8 eighth-partials within the oct group
            #pragma unroll
            for (int m = 1; m < 8; m <<= 1)
                #pragma unroll
                for (int r = 0; r < 8; ++r)
                    acc[r] += __shfl_xor(acc[r], m);
            if (p == 0) {
                float4 lo = make_float4(acc[0] + bh[0], acc[1] + bh[1],
                                        acc[2] + bh[2], acc[3] + bh[3]);
                float4 hi = make_float4(acc[4] + bh[4], acc[5] + bh[5],
                                        acc[6] + bh[6], acc[7] + bh[7]);
                *(float4*)&gh_s[8 * ro]     = lo;
                *(float4*)&gh_s[8 * ro + 4] = hi;
            }
        }
        __syncthreads();

        if (tid < Hq) {
            const float r = 1.f / (1.f + __expf(-(gi_s[tid]       + gh_s[tid])));
            const float z = 1.f / (1.f + __expf(-(gi_s[150 + tid] + gh_s[150 + tid])));
            const float nv = tanhf(gi_s[300 + tid] + r * gh_s[300 + tid]);
            const int slot = (tid / 19) * 20 + (tid % 19);
            const float hn = (1.f - z) * nv + z * hbuf[slot];
            hbuf[slot] = hn;
            stage[(s & 63) * 150 + tid] = hn;   // LDS history, no global store
        }
        __syncthreads();

        // periodic cooperative flush of the h history
        if ((s & 63) == 63 || s == TCr - 1) {
            const int sf0 = s & ~63;
            const int nf2 = (s - sf0 + 1) * 75;        // float2 count
            for (int idx = tid; idx < nf2; idx += 512) {
                const int rrow = idx / 75, cc = idx % 75;
                const int ss = sf0 + rrow;
                const int ltw = dir ? (TCr - 1 - ss) : ss;
                *(float2*)(seqb + (size_t)(t0 + ltw) * D2 + 2 * cc) =
                    *(const float2*)&stage[rrow * 150 + 2 * cc];
            }
        }

        gval = gnext;
        lt = ltn;
    }

    if (tid < Hq) hs[tid] = hbuf[(tid / 19) * 20 + (tid % 19)];
}

// ---------------------------------------------------------------------------
// Kernel 3a: ctxW[k][d] = battn[k][d] + sum_c attn_context[k][c]*Wattn[k][c][d]
// ---------------------------------------------------------------------------
__global__ void ctxw_kernel(
    const float* __restrict__ attn_context,
    const float* __restrict__ Wattn,
    const float* __restrict__ battn,
    float* __restrict__ ctxW)
{
    const int o = blockIdx.x * 256 + threadIdx.x;
    if (o >= Kq * D2) return;
    const int k = o / D2, d = o % D2;
    float acc = battn[o];
    const float* Wp = Wattn + ((size_t)k * (Cq + D2)) * D2 + d;
    for (int c = 0; c < Cq; ++c)
        acc += attn_context[k * Cq + c] * Wp[(size_t)c * D2];
    ctxW[o] = acc;
}

// ---------------------------------------------------------------------------
// Kernel 3b: context[b][k][:] = tanh(ctxW[k] + hidden[b] @ Wattn[k,300:,:])
// ---------------------------------------------------------------------------
__global__ __launch_bounds__(256) void ctx_compute(
    const float* __restrict__ seq,
    const float* __restrict__ Wattn,
    const float* __restrict__ ctxW,
    float* __restrict__ context,      // [B][6][300]
    float* __restrict__ normsq)       // [B][6]
{
    const int b = blockIdx.x;
    const int k = blockIdx.y;
    const int tid = threadIdx.x;
    const int lane = tid & 63, wv = tid >> 6;

    __shared__ float hb[304];
    __shared__ float red[4];

    for (int i = tid; i < D2; i += 256)
        hb[i] = (i < Hq) ? seq[((size_t)b * Tq + (Tq - 1)) * D2 + i]
                         : seq[(size_t)b * Tq * D2 + i];
    __syncthreads();

    float ssq = 0.f;
    for (int d = tid; d < D2; d += 256) {
        float acc = ctxW[k * D2 + d];
        const float* Wp = Wattn + ((size_t)k * (Cq + D2) + Cq) * D2 + d;
        for (int jj = 0; jj < D2; ++jj)
            acc += hb[jj] * Wp[(size_t)jj * D2];
        const float c = tanhf(acc);
        context[((size_t)b * Kq + k) * D2 + d] = c;
        ssq += c * c;
    }
    for (int off = 32; off > 0; off >>= 1) ssq += __shfl_xor(ssq, off, 64);
    if (lane == 0) red[wv] = ssq;
    __syncthreads();
    if (tid == 0) normsq[b * Kq + k] = red[0] + red[1] + red[2] + red[3];
}

// ---------------------------------------------------------------------------
// Kernel 3c: gram regularizer per b
// ---------------------------------------------------------------------------
__global__ __launch_bounds__(256) void gram_kernel(
    const float* __restrict__ context,
    const float* __restrict__ normsq,
    float* __restrict__ regbuf)
{
    const int b = blockIdx.x;
    const int tid = threadIdx.x;
    __shared__ float ctx[Kq * D2];
    __shared__ float Gm[36];

    for (int o = tid; o < Kq * D2; o += 256)
        ctx[o] = context[(size_t)b * Kq * D2 + o];
    __syncthreads();

    if (tid < 36) {
        const int k = tid / 6, jj = tid % 6;
        float g = 0.f;
        for (int d = 0; d < D2; ++d)
            g += ctx[k * D2 + d] * ctx[jj * D2 + d];
        const float nk = fmaxf(sqrtf(normsq[b * Kq + k]), 1e-12f);
        const float nj = fmaxf(sqrtf(normsq[b * Kq + jj]), 1e-12f);
        g /= (nk * nj);
        const float diff = g - ((k == jj) ? 1.f : 0.f);
        Gm[tid] = diff * diff;
    }
    __syncthreads();
    if (tid == 0) {
        float s = 0.f;
        for (int i = 0; i < 36; ++i) s += Gm[i];
        regbuf[b] = sqrtf(s);
    }
}

// ---------------------------------------------------------------------------
// Kernel 4a: energy[b][t][k] = seq[b][t] . context[b][k]   grid (8, B)
// ---------------------------------------------------------------------------
__global__ __launch_bounds__(256) void energy_kernel(
    const float* __restrict__ seq,
    const float* __restrict__ context,
    float* __restrict__ en)           // [B][512][6]
{
    const int tc = blockIdx.x;
    const int b  = blockIdx.y;
    const int tid = threadIdx.x;
    const int lane = tid & 63, wv = tid >> 6;

    __shared__ float ctx[Kq * D2];
    for (int o = tid; o < Kq * D2; o += 256)
        ctx[o] = context[(size_t)b * Kq * D2 + o];
    __syncthreads();

    const float* seqb = seq + (size_t)b * Tq * D2;
    for (int s = 0; s < 16; ++s) {
        const int tt = tc * 64 + s * 4 + wv;
        float acc[Kq] = {0.f,0.f,0.f,0.f,0.f,0.f};
        for (int d = lane; d < D2; d += 64) {
            const float sv = seqb[(size_t)tt * D2 + d];
            #pragma unroll
            for (int k = 0; k < Kq; ++k) acc[k] += sv * ctx[k * D2 + d];
        }
        #pragma unroll
        for (int k = 0; k < Kq; ++k) {
            float v = acc[k];
            for (int off = 32; off > 0; off >>= 1) v += __shfl_xor(v, off, 64);
            if (lane == 0) en[((size_t)b * Tq + tt) * Kq + k] = v;
        }
    }
}

// ---------------------------------------------------------------------------
// Kernel 4b: softmax over t per (b,k), in-place on en.  grid (B)
// ---------------------------------------------------------------------------
__global__ __launch_bounds__(256) void softmax_kernel(float* __restrict__ en)
{
    const int b = blockIdx.x;
    const int tid = threadIdx.x;
    const int lane = tid & 63, wv = tid >> 6;
    __shared__ float es[Tq * Kq];
    __shared__ float red[8];

    for (int o = tid; o < Tq * Kq; o += 256)
        es[o] = en[(size_t)b * Tq * Kq + o];
    __syncthreads();

    for (int k = 0; k < Kq; ++k) {
        float m = -1e30f;
        for (int tt = tid; tt < Tq; tt += 256) m = fmaxf(m, es[tt * Kq + k]);
        for (int off = 32; off > 0; off >>= 1) m = fmaxf(m, __shfl_xor(m, off, 64));
        if (lane == 0) red[wv] = m;
        __syncthreads();
        m = fmaxf(fmaxf(red[0], red[1]), fmaxf(red[2], red[3]));
        float ssum = 0.f;
        for (int tt = tid; tt < Tq; tt += 256) {
            const float e = __expf(es[tt * Kq + k] - m);
            es[tt * Kq + k] = e;
            ssum += e;
        }
        for (int off = 32; off > 0; off >>= 1) ssum += __shfl_xor(ssum, off, 64);
        if (lane == 0) red[4 + wv] = ssum;
        __syncthreads();
        const float inv = 1.f / (red[4] + red[5] + red[6] + red[7]);
        for (int tt = tid; tt < Tq; tt += 256) es[tt * Kq + k] *= inv;
        __syncthreads();
    }

    for (int o = tid; o < Tq * Kq; o += 256)
        en[(size_t)b * Tq * Kq + o] = es[o];
}

// ---------------------------------------------------------------------------
// Kernel 4c: pooled partials over 64-t chunks.  grid (8, B)
// ---------------------------------------------------------------------------
__global__ __launch_bounds__(256) void pooledp_kernel(
    const float* __restrict__ seq,
    const float* __restrict__ en,     // probs now
    float* __restrict__ partial)      // [B*8][1800]
{
    const int tc = blockIdx.x;
    const int b  = blockIdx.y;
    const int tid = threadIdx.x;
    const int lane = tid & 63, wv = tid >> 6;

    __shared__ float pr[64 * Kq];
    __shared__ float part[4][Kq * D2];   // 28.8 KB

    if (tid < 64 * Kq / 2) {
        pr[tid]       = en[((size_t)b * Tq + tc * 64) * Kq + tid];
        pr[tid + 192] = en[((size_t)b * Tq + tc * 64) * Kq + tid + 192];
    }
    __syncthreads();

    const float* seqb = seq + (size_t)b * Tq * D2;

    float pp[Kq][5];
    #pragma unroll
    for (int k = 0; k < Kq; ++k)
        #pragma unroll
        for (int q = 0; q < 5; ++q) pp[k][q] = 0.f;

    for (int s = 0; s < 16; ++s) {
        const int tl = s * 4 + wv;
        const int tt = tc * 64 + tl;
        float prr[Kq];
        #pragma unroll
        for (int k = 0; k < Kq; ++k) prr[k] = pr[tl * Kq + k];
        #pragma unroll
        for (int q = 0; q < 5; ++q) {
            const int d = lane + q * 64;
            const float sv = (d < D2) ? seqb[(size_t)tt * D2 + d] : 0.f;
            #pragma unroll
            for (int k = 0; k < Kq; ++k) pp[k][q] += prr[k] * sv;
        }
    }
    #pragma unroll
    for (int k = 0; k < Kq; ++k)
        #pragma unroll
        for (int q = 0; q < 5; ++q) {
            const int d = lane + q * 64;
            if (d < D2) part[wv][k * D2 + d] = pp[k][q];
        }
    __syncthreads();
    float* op = partial + ((size_t)b * 8 + tc) * (Kq * D2);
    for (int o = tid; o < Kq * D2; o += 256)
        op[o] = part[0][o] + part[1][o] + part[2][o] + part[3][o];
}

// ---------------------------------------------------------------------------
// Kernel 4d: final: pooled reduce -> topic -> logits -> softmax.  grid (B)
// ---------------------------------------------------------------------------
__global__ __launch_bounds__(256) void final_kernel(
    const float* __restrict__ partial,
    const float* __restrict__ Wtop,
    const float* __restrict__ btop,
    const float* __restrict__ Wout,
    const float* __restrict__ bout,
    float* __restrict__ outp)
{
    const int b = blockIdx.x;
    const int tid = threadIdx.x;
    __shared__ float pooled[Kq * D2];
    __shared__ float feats[Kq * THq];
    __shared__ float lsm[8];

    for (int o = tid; o < Kq * D2; o += 256) {
        float s = 0.f;
        #pragma unroll
        for (int c = 0; c < 8; ++c)
            s += partial[((size_t)b * 8 + c) * (Kq * D2) + o];
        pooled[o] = s;
    }
    __syncthreads();

    if (tid < Kq * THq) {
        const int k = tid / THq, hh = tid % THq;
        float acc = btop[tid];
        const float* wp = Wtop + (size_t)k * D2 * THq + hh;
        for (int d = 0; d < D2; ++d)
            acc += pooled[k * D2 + d] * wp[(size_t)d * THq];
        feats[tid] = fmaxf(acc, 0.f);
    }
    __syncthreads();

    if (tid < CLSq) {
        float acc = bout[tid];
        for (int f = 0; f < Kq * THq; ++f)
            acc += feats[f] * Wout[f * CLSq + tid];
        lsm[tid] = acc;
    }
    __syncthreads();
    if (tid < CLSq) {
        float m = lsm[0];
        for (int c = 1; c < CLSq; ++c) m = fmaxf(m, lsm[c]);
        float s = 0.f;
        for (int c = 0; c < CLSq; ++c) s += __expf(lsm[c] - m);
        outp[(size_t)b * CLSq + tid] = __expf(lsm[tid] - m) / s;
    }
}

// ---------------------------------------------------------------------------
// Kernel 5: reg = mean_b regbuf[b]  -> d_out[640]
// ---------------------------------------------------------------------------
__global__ void reg_final(const float* __restrict__ regbuf, float* __restrict__ outp)
{
    const int tid = threadIdx.x;   // 128 threads
    float v = regbuf[tid];
    for (int off = 32; off > 0; off >>= 1) v += __shfl_xor(v, off, 64);
    __shared__ float r2[2];
    if ((tid & 63) == 0) r2[tid >> 6] = v;
    __syncthreads();
    if (tid == 0) outp[Bq * CLSq] = (r2[0] + r2[1]) * (1.f / (float)Bq);
}

// ---------------------------------------------------------------------------
extern "C" void kernel_launch(void* const* d_in, const int* in_sizes, int n_in,
                              void* d_out, int out_size, void* d_ws, size_t ws_size,
                              hipStream_t stream)
{
    const float* x     = (const float*)d_in[0];
    const float* Wih_f = (const float*)d_in[1];
    const float* Whh_f = (const float*)d_in[2];
    const float* bih_f = (const float*)d_in[3];
    const float* bhh_f = (const float*)d_in[4];
    const float* Wih_b = (const float*)d_in[5];
    const float* Whh_b = (const float*)d_in[6];
    const float* bih_b = (const float*)d_in[7];
    const float* bhh_b = (const float*)d_in[8];
    const float* attn_context = (const float*)d_in[9];
    const float* Wattn = (const float*)d_in[10];
    const float* battn = (const float*)d_in[11];
    const float* Wtop  = (const float*)d_in[12];
    const float* btop  = (const float*)d_in[13];
    const float* Wout  = (const float*)d_in[14];
    const float* bout  = (const float*)d_in[15];
    float* outp = (float*)d_out;

    // fixed workspace layout (float units)
    float* ws       = (float*)d_ws;
    float* seqv     = ws;                                   // 19,660,800
    float* hstate   = seqv + (size_t)Bq * Tq * D2;          // 38,400
    float* ctxW     = hstate + (size_t)2 * Bq * Hq;         // 1,800
    float* context  = ctxW + Kq * D2;                       // 230,400
    float* regbuf   = context + (size_t)Bq * Kq * D2;       // 128
    float* normsq   = regbuf + Bq;                          // 768
    float* en       = normsq + Bq * Kq;                     // 393,216
    float* partial  = en + (size_t)Bq * Tq * Kq;            // 1,843,200
    __hip_bfloat16* xb16 = (__hip_bfloat16*)(partial + (size_t)Bq * 8 * Kq * D2); // 19,660,800 bf16
    __hip_bfloat16* Wb16 = xb16 + (size_t)Bq * Tq * Iq;     // 270,000 bf16
    float* gi_chunk = (float*)(Wb16 + (size_t)2 * G3 * Iq); // 115200*TCr fp32
    const size_t fixed_floats = (size_t)(gi_chunk - ws);

    // pick largest TCr in {256,128,64,32} that fits ws_size
    int tcShift = 5;
    for (int sh = 8; sh >= 5; --sh) {
        size_t need = (fixed_floats + (size_t)115200 * (1 << sh)) * 4;
        if (need <= ws_size) { tcShift = sh; break; }
    }
    const int TCr = 1 << tcShift;
    const int NL = Tq / TCr;

    // one-time bf16 casts (x, Wih_f, Wih_b)
    cast_bf16_kernel<<<dim3((Bq * Tq * Iq / 4 + 255) / 256), 256, 0, stream>>>(
        x, xb16, Bq * Tq * Iq / 4);
    cast_bf16_kernel<<<dim3((G3 * Iq / 4 + 255) / 256), 256, 0, stream>>>(
        Wih_f, Wb16, G3 * Iq / 4);
    cast_bf16_kernel<<<dim3((G3 * Iq / 4 + 255) / 256), 256, 0, stream>>>(
        Wih_b, Wb16 + (size_t)G3 * Iq, G3 * Iq / 4);

    for (int c = 0; c < NL; ++c) {
        const int t0f = c * TCr;
        const int t0b = Tq - TCr * (c + 1);
        gi_gemm_mfma<<<dim3(4, Bq * TCr / 128, 2), 256, 0, stream>>>(
            xb16, Wb16, bih_f, bih_b, gi_chunk, t0f, t0b, tcShift);
        gru_rec<<<dim3(2 * Bq), 512, 0, stream>>>(
            gi_chunk, Whh_f, bhh_f, Whh_b, bhh_b, hstate, seqv, c, tcShift);
    }

    ctxw_kernel<<<dim3((Kq * D2 + 255) / 256), 256, 0, stream>>>(
        attn_context, Wattn, battn, ctxW);
    ctx_compute<<<dim3(Bq, Kq), 256, 0, stream>>>(seqv, Wattn, ctxW, context, normsq);
    gram_kernel<<<dim3(Bq), 256, 0, stream>>>(context, normsq, regbuf);
    energy_kernel<<<dim3(8, Bq), 256, 0, stream>>>(seqv, context, en);
    softmax_kernel<<<dim3(Bq), 256, 0, stream>>>(en);
    pooledp_kernel<<<dim3(8, Bq), 256, 0, stream>>>(seqv, en, partial);
    final_kernel<<<dim3(Bq), 256, 0, stream>>>(partial, Wtop, btop, Wout, bout, outp);
    reg_final<<<dim3(1), 128, 0, stream>>>(regbuf, outp);
}

// Round 8
// 1046.900 us; speedup vs baseline: 1.1428x; 1.1428x over previous
//
#include <hip/hip_runtime.h>
#include <hip/hip_bf16.h>
#include <math.h>

// Problem constants
#define Bq   128
#define Tq   512
#define Iq   300   // input dim
#define Hq   150   // hidden per dir
#define G3   450   // 3*H
#define Kq   6
#define Cq   300
#define D2   300   // 2*H
#define THq  20
#define CLSq 5

typedef __attribute__((ext_vector_type(8))) short short8;     // 8 bf16 (4 VGPR) MFMA A/B frag
typedef __attribute__((ext_vector_type(4))) float floatx4;    // MFMA C/D frag

// ---------------------------------------------------------------------------
// Kernel 0: fp32 -> bf16 cast (RNE). n4 = n/4.
// ---------------------------------------------------------------------------
__global__ __launch_bounds__(256) void cast_bf16_kernel(
    const float* __restrict__ in, __hip_bfloat16* __restrict__ out, int n4)
{
    const int i = blockIdx.x * 256 + threadIdx.x;
    if (i < n4) {
        float4 v = *(const float4*)(in + 4 * (size_t)i);
        out[4 * (size_t)i + 0] = __float2bfloat16(v.x);
        out[4 * (size_t)i + 1] = __float2bfloat16(v.y);
        out[4 * (size_t)i + 2] = __float2bfloat16(v.z);
        out[4 * (size_t)i + 3] = __float2bfloat16(v.w);
    }
}

// ---------------------------------------------------------------------------
// Kernel 1: gi GEMM via bf16 MFMA 16x16x32 (verified layouts, R6-proven).
// ---------------------------------------------------------------------------
#define LB 40

__global__ __launch_bounds__(256) void gi_gemm_mfma(
    const __hip_bfloat16* __restrict__ xb,    // [B][T][300] bf16
    const __hip_bfloat16* __restrict__ Wbf,   // [2][450][300] bf16
    const float* __restrict__ bf_, const float* __restrict__ bb_,
    float* __restrict__ gic, int t0f, int t0b, int tcShift)
{
    const int dir = blockIdx.z;
    const unsigned short* W = (const unsigned short*)(Wbf + (size_t)dir * G3 * Iq);
    const unsigned short* X = (const unsigned short*)xb;
    const float* bias = dir ? bb_ : bf_;
    const int t0 = dir ? t0b : t0f;
    const int TCr = 1 << tcShift;
    float* outb = gic + (size_t)dir * Bq * TCr * G3;

    const int m0 = blockIdx.y * 128;
    const int n0 = blockIdx.x * 128;
    const int tid  = threadIdx.x;
    const int wv   = tid >> 6, lane = tid & 63;
    const int wm   = wv & 1,  wn   = wv >> 1;
    const int quad = lane >> 4, mr = lane & 15;

    __shared__ __align__(16) unsigned short Ab[128 * LB];
    __shared__ __align__(16) unsigned short Bb[128 * LB];

    floatx4 acc[4][4];
    #pragma unroll
    for (int i = 0; i < 4; ++i)
        #pragma unroll
        for (int j = 0; j < 4; ++j)
            acc[i][j] = (floatx4){0.f, 0.f, 0.f, 0.f};

    for (int k0 = 0; k0 < 320; k0 += 32) {
        __syncthreads();
        #pragma unroll
        for (int i = 0; i < 4; ++i) {
            const int g = tid + 256 * i;         // 0..1023
            const int row = g >> 3, kq = g & 7;  // 4-bf16 granule
            const int k = k0 + kq * 4;
            const int r = m0 + row;
            const int bb2 = r >> tcShift, lt = r & (TCr - 1);
            ushort4 av = make_ushort4(0, 0, 0, 0);
            if (k < Iq)
                av = *(const ushort4*)(X + ((size_t)bb2 * Tq + t0 + lt) * Iq + k);
            *(ushort4*)&Ab[row * LB + kq * 4] = av;
            const int n = n0 + row;
            ushort4 bv = make_ushort4(0, 0, 0, 0);
            if (n < G3 && k < Iq)
                bv = *(const ushort4*)(W + (size_t)n * Iq + k);
            *(ushort4*)&Bb[row * LB + kq * 4] = bv;
        }
        __syncthreads();

        short8 af[4], bfr[4];
        #pragma unroll
        for (int i = 0; i < 4; ++i)
            af[i] = *(const short8*)&Ab[(wm * 64 + i * 16 + mr) * LB + quad * 8];
        #pragma unroll
        for (int j = 0; j < 4; ++j)
            bfr[j] = *(const short8*)&Bb[(wn * 64 + j * 16 + mr) * LB + quad * 8];
        #pragma unroll
        for (int i = 0; i < 4; ++i)
            #pragma unroll
            for (int j = 0; j < 4; ++j)
                acc[i][j] = __builtin_amdgcn_mfma_f32_16x16x32_bf16(
                    af[i], bfr[j], acc[i][j], 0, 0, 0);
    }

    #pragma unroll
    for (int j = 0; j < 4; ++j) {
        const int gn = n0 + wn * 64 + j * 16 + mr;
        if (gn >= G3) continue;
        const float bv = bias[gn];
        #pragma unroll
        for (int i = 0; i < 4; ++i) {
            const int mbase = m0 + wm * 64 + i * 16 + quad * 4;
            #pragma unroll
            for (int rg = 0; rg < 4; ++rg)
                outb[(size_t)(mbase + rg) * G3 + gn] = acc[i][j][rg] + bv;
        }
    }
}

// ---------------------------------------------------------------------------
// Kernel 2: GRU recurrence, quarter-split rows, LDS-partial combine.
// Thread t = (row-quad rq=t>>2, quarter p=t&3): owns Whh rows 4rq..4rq+3
// restricted to h-cols [p*38, p*38+38) (p=3: 36 valid) = 152 useful weights
// (160 with pad; proven non-spilling scale). h in LDS quarter-padded
// (quarter p at float offset p*40; the 4 read-address groups hit disjoint
// bank quads -> conflict-free). Per lane per step: 10 ds_read_b128 + 1
// ds_write_b128 partial. NO shuffles (R7 lesson: __shfl = ds_bpermute on
// the same LDS pipe, and multi-round reductions serialize). Gate stage sums
// the 4 partials straight from LDS (12 b32 reads over ~2.3 waves).
// ---------------------------------------------------------------------------
__global__ __launch_bounds__(512, 2) void gru_rec(
    const float* __restrict__ gic,     // [2][B][TCr][450]
    const float* __restrict__ Whh_f, const float* __restrict__ bhh_f,
    const float* __restrict__ Whh_b, const float* __restrict__ bhh_b,
    float* __restrict__ hstate,        // [2][B][150]
    float* __restrict__ seq,           // [B][T][300]
    int chunk, int tcShift)
{
    const int TCr = 1 << tcShift;
    const int bid = blockIdx.x;
    const int dir = bid & 1;
    const int b   = bid >> 1;
    const float* Whh = dir ? Whh_b : Whh_f;
    const float* bhh = dir ? bhh_b : bhh_f;
    const int tid = threadIdx.x;
    const int rq  = tid >> 2;          // row-quad (rows 4rq..4rq+3), valid < 113
    const int p   = tid & 3;           // h-quarter
    const bool gact = (rq < 113);      // gemv role
    const bool iact = (tid < 450);     // gi-stage role

    __shared__ __align__(16) float stage[64 * 150];  // W-staging, then h history
    __shared__ __align__(16) float4 hbuf4[40];       // h quarter-padded: 4 x 40 floats
    __shared__ __align__(16) float ghp[4][456];      // per-quarter gemv partials
    __shared__ float gi_s[456];
    float* hbuf = (float*)hbuf4;

    // weights: w[r][c] = Whh[4rq+r][p*38+c], c<38 (p=3: c<36), else 0
    float w[4][40];

    for (int c = 0; c < 8; ++c) {
        const int r0 = c * 64;
        const int nrows = (r0 + 64 <= G3) ? 64 : (G3 - r0);
        const int nel = nrows * 150;
        __syncthreads();
        for (int idx = tid * 4; idx < nel; idx += 512 * 4)
            *(float4*)&stage[idx] = *(const float4*)(Whh + (size_t)r0 * 150 + idx);
        __syncthreads();
        if (gact && (rq >> 4) == c) {
            const int rl = 4 * rq - r0;             // 0..60, multiple of 4
            const int cmax = (p == 3) ? 36 : 38;
            #pragma unroll
            for (int r = 0; r < 4; ++r) {
                const bool rv = (4 * rq + r < G3);
                #pragma unroll
                for (int cc = 0; cc < 40; ++cc)
                    w[r][cc] = (rv && cc < cmax)
                             ? stage[(rl + r) * 150 + p * 38 + cc] : 0.f;
            }
        }
    }

    // gate-lane constants (tid < 150): biases and h slot
    float bh3[3] = {0.f, 0.f, 0.f};
    if (tid < Hq) {
        bh3[0] = bhh[tid];
        bh3[1] = bhh[150 + tid];
        bh3[2] = bhh[300 + tid];
    }
    const int hslot = (tid / 38) * 40 + (tid % 38);  // valid when tid < 150

    float* hs = hstate + (size_t)(dir * Bq + b) * Hq;
    if (tid < 160) {
        const int pp = tid / 40, off = tid % 40;
        const int j = pp * 38 + off;
        hbuf[tid] = (off < 38 && j < Hq && chunk > 0) ? hs[j] : 0.f;
    }
    __syncthreads();

    const float* gib = gic + (size_t)(dir * Bq + b) * TCr * G3;
    const int t0 = dir ? (Tq - TCr * (chunk + 1)) : (chunk * TCr);
    float* seqb = seq + (size_t)b * Tq * D2 + dir * Hq;

    int lt = dir ? (TCr - 1) : 0;
    float gval = iact ? gib[(size_t)lt * G3 + tid] : 0.f;

    for (int s = 0; s < TCr; ++s) {
        const int ltn = dir ? (TCr - 2 - s) : (s + 1);
        float gnext = 0.f;
        if (s + 1 < TCr && iact)
            gnext = gib[(size_t)ltn * G3 + tid];

        if (iact) gi_s[tid] = gval;

        if (gact) {
            const float4* hh = hbuf4 + p * 10;   // this lane's h-quarter
            float acc0 = 0.f, acc1 = 0.f, acc2 = 0.f, acc3 = 0.f;
            #pragma unroll
            for (int q = 0; q < 10; ++q) {
                const float4 hv = hh[q];         // 4-group broadcast read
                acc0 += hv.x * w[0][4*q]   + hv.y * w[0][4*q+1]
                      + hv.z * w[0][4*q+2] + hv.w * w[0][4*q+3];
                acc1 += hv.x * w[1][4*q]   + hv.y * w[1][4*q+1]
                      + hv.z * w[1][4*q+2] + hv.w * w[1][4*q+3];
                acc2 += hv.x * w[2][4*q]   + hv.y * w[2][4*q+1]
                      + hv.z * w[2][4*q+2] + hv.w * w[2][4*q+3];
                acc3 += hv.x * w[3][4*q]   + hv.y * w[3][4*q+1]
                      + hv.z * w[3][4*q+2] + hv.w * w[3][4*q+3];
            }
            *(float4*)&ghp[p][4 * rq] = make_float4(acc0, acc1, acc2, acc3);
        }
        __syncthreads();

        if (tid < Hq) {
            const float ghr = ghp[0][tid] + ghp[1][tid]
                            + ghp[2][tid] + ghp[3][tid] + bh3[0];
            const float ghz = ghp[0][150+tid] + ghp[1][150+tid]
                            + ghp[2][150+tid] + ghp[3][150+tid] + bh3[1];
            const float ghn = ghp[0][300+tid] + ghp[1][300+tid]
                            + ghp[2][300+tid] + ghp[3][300+tid] + bh3[2];
            const float r = 1.f / (1.f + __expf(-(gi_s[tid]       + ghr)));
            const float z = 1.f / (1.f + __expf(-(gi_s[150 + tid] + ghz)));
            const float nv = tanhf(gi_s[300 + tid] + r * ghn);
            const float hn = (1.f - z) * nv + z * hbuf[hslot];
            hbuf[hslot] = hn;
            stage[(s & 63) * 150 + tid] = hn;   // LDS history, no global store
        }
        __syncthreads();

        // periodic cooperative flush of the h history
        if ((s & 63) == 63 || s == TCr - 1) {
            const int sf0 = s & ~63;
            const int nf2 = (s - sf0 + 1) * 75;        // float2 count
            for (int idx = tid; idx < nf2; idx += 512) {
                const int rrow = idx / 75, cc = idx % 75;
                const int ss = sf0 + rrow;
                const int ltw = dir ? (TCr - 1 - ss) : ss;
                *(float2*)(seqb + (size_t)(t0 + ltw) * D2 + 2 * cc) =
                    *(const float2*)&stage[rrow * 150 + 2 * cc];
            }
        }

        gval = gnext;
        lt = ltn;
    }

    if (tid < Hq) hs[tid] = hbuf[hslot];
}

// ---------------------------------------------------------------------------
// Kernel 3a: ctxW[k][d] = battn[k][d] + sum_c attn_context[k][c]*Wattn[k][c][d]
// ---------------------------------------------------------------------------
__global__ void ctxw_kernel(
    const float* __restrict__ attn_context,
    const float* __restrict__ Wattn,
    const float* __restrict__ battn,
    float* __restrict__ ctxW)
{
    const int o = blockIdx.x * 256 + threadIdx.x;
    if (o >= Kq * D2) return;
    const int k = o / D2, d = o % D2;
    float acc = battn[o];
    const float* Wp = Wattn + ((size_t)k * (Cq + D2)) * D2 + d;
    for (int c = 0; c < Cq; ++c)
        acc += attn_context[k * Cq + c] * Wp[(size_t)c * D2];
    ctxW[o] = acc;
}

// ---------------------------------------------------------------------------
// Kernel 3b: context[b][k][:] = tanh(ctxW[k] + hidden[b] @ Wattn[k,300:,:])
// ---------------------------------------------------------------------------
__global__ __launch_bounds__(256) void ctx_compute(
    const float* __restrict__ seq,
    const float* __restrict__ Wattn,
    const float* __restrict__ ctxW,
    float* __restrict__ context,      // [B][6][300]
    float* __restrict__ normsq)       // [B][6]
{
    const int b = blockIdx.x;
    const int k = blockIdx.y;
    const int tid = threadIdx.x;
    const int lane = tid & 63, wv = tid >> 6;

    __shared__ float hb[304];
    __shared__ float red[4];

    for (int i = tid; i < D2; i += 256)
        hb[i] = (i < Hq) ? seq[((size_t)b * Tq + (Tq - 1)) * D2 + i]
                         : seq[(size_t)b * Tq * D2 + i];
    __syncthreads();

    float ssq = 0.f;
    for (int d = tid; d < D2; d += 256) {
        float acc = ctxW[k * D2 + d];
        const float* Wp = Wattn + ((size_t)k * (Cq + D2) + Cq) * D2 + d;
        for (int jj = 0; jj < D2; ++jj)
            acc += hb[jj] * Wp[(size_t)jj * D2];
        const float c = tanhf(acc);
        context[((size_t)b * Kq + k) * D2 + d] = c;
        ssq += c * c;
    }
    for (int off = 32; off > 0; off >>= 1) ssq += __shfl_xor(ssq, off, 64);
    if (lane == 0) red[wv] = ssq;
    __syncthreads();
    if (tid == 0) normsq[b * Kq + k] = red[0] + red[1] + red[2] + red[3];
}

// ---------------------------------------------------------------------------
// Kernel 3c: gram regularizer per b
// ---------------------------------------------------------------------------
__global__ __launch_bounds__(256) void gram_kernel(
    const float* __restrict__ context,
    const float* __restrict__ normsq,
    float* __restrict__ regbuf)
{
    const int b = blockIdx.x;
    const int tid = threadIdx.x;
    __shared__ float ctx[Kq * D2];
    __shared__ float Gm[36];

    for (int o = tid; o < Kq * D2; o += 256)
        ctx[o] = context[(size_t)b * Kq * D2 + o];
    __syncthreads();

    if (tid < 36) {
        const int k = tid / 6, jj = tid % 6;
        float g = 0.f;
        for (int d = 0; d < D2; ++d)
            g += ctx[k * D2 + d] * ctx[jj * D2 + d];
        const float nk = fmaxf(sqrtf(normsq[b * Kq + k]), 1e-12f);
        const float nj = fmaxf(sqrtf(normsq[b * Kq + jj]), 1e-12f);
        g /= (nk * nj);
        const float diff = g - ((k == jj) ? 1.f : 0.f);
        Gm[tid] = diff * diff;
    }
    __syncthreads();
    if (tid == 0) {
        float s = 0.f;
        for (int i = 0; i < 36; ++i) s += Gm[i];
        regbuf[b] = sqrtf(s);
    }
}

// ---------------------------------------------------------------------------
// Kernel 4a: energy[b][t][k] = seq[b][t] . context[b][k]   grid (8, B)
// ---------------------------------------------------------------------------
__global__ __launch_bounds__(256) void energy_kernel(
    const float* __restrict__ seq,
    const float* __restrict__ context,
    float* __restrict__ en)           // [B][512][6]
{
    const int tc = blockIdx.x;
    const int b  = blockIdx.y;
    const int tid = threadIdx.x;
    const int lane = tid & 63, wv = tid >> 6;

    __shared__ float ctx[Kq * D2];
    for (int o = tid; o < Kq * D2; o += 256)
        ctx[o] = context[(size_t)b * Kq * D2 + o];
    __syncthreads();

    const float* seqb = seq + (size_t)b * Tq * D2;
    for (int s = 0; s < 16; ++s) {
        const int tt = tc * 64 + s * 4 + wv;
        float acc[Kq] = {0.f,0.f,0.f,0.f,0.f,0.f};
        for (int d = lane; d < D2; d += 64) {
            const float sv = seqb[(size_t)tt * D2 + d];
            #pragma unroll
            for (int k = 0; k < Kq; ++k) acc[k] += sv * ctx[k * D2 + d];
        }
        #pragma unroll
        for (int k = 0; k < Kq; ++k) {
            float v = acc[k];
            for (int off = 32; off > 0; off >>= 1) v += __shfl_xor(v, off, 64);
            if (lane == 0) en[((size_t)b * Tq + tt) * Kq + k] = v;
        }
    }
}

// ---------------------------------------------------------------------------
// Kernel 4b: softmax over t per (b,k), in-place on en.  grid (B)
// ---------------------------------------------------------------------------
__global__ __launch_bounds__(256) void softmax_kernel(float* __restrict__ en)
{
    const int b = blockIdx.x;
    const int tid = threadIdx.x;
    const int lane = tid & 63, wv = tid >> 6;
    __shared__ float es[Tq * Kq];
    __shared__ float red[8];

    for (int o = tid; o < Tq * Kq; o += 256)
        es[o] = en[(size_t)b * Tq * Kq + o];
    __syncthreads();

    for (int k = 0; k < Kq; ++k) {
        float m = -1e30f;
        for (int tt = tid; tt < Tq; tt += 256) m = fmaxf(m, es[tt * Kq + k]);
        for (int off = 32; off > 0; off >>= 1) m = fmaxf(m, __shfl_xor(m, off, 64));
        if (lane == 0) red[wv] = m;
        __syncthreads();
        m = fmaxf(fmaxf(red[0], red[1]), fmaxf(red[2], red[3]));
        float ssum = 0.f;
        for (int tt = tid; tt < Tq; tt += 256) {
            const float e = __expf(es[tt * Kq + k] - m);
            es[tt * Kq + k] = e;
            ssum += e;
        }
        for (int off = 32; off > 0; off >>= 1) ssum += __shfl_xor(ssum, off, 64);
        if (lane == 0) red[4 + wv] = ssum;
        __syncthreads();
        const float inv = 1.f / (red[4] + red[5] + red[6] + red[7]);
        for (int tt = tid; tt < Tq; tt += 256) es[tt * Kq + k] *= inv;
        __syncthreads();
    }

    for (int o = tid; o < Tq * Kq; o += 256)
        en[(size_t)b * Tq * Kq + o] = es[o];
}

// ---------------------------------------------------------------------------
// Kernel 4c: pooled partials over 64-t chunks.  grid (8, B)
// ---------------------------------------------------------------------------
__global__ __launch_bounds__(256) void pooledp_kernel(
    const float* __restrict__ seq,
    const float* __restrict__ en,     // probs now
    float* __restrict__ partial)      // [B*8][1800]
{
    const int tc = blockIdx.x;
    const int b  = blockIdx.y;
    const int tid = threadIdx.x;
    const int lane = tid & 63, wv = tid >> 6;

    __shared__ float pr[64 * Kq];
    __shared__ float part[4][Kq * D2];   // 28.8 KB

    if (tid < 64 * Kq / 2) {
        pr[tid]       = en[((size_t)b * Tq + tc * 64) * Kq + tid];
        pr[tid + 192] = en[((size_t)b * Tq + tc * 64) * Kq + tid + 192];
    }
    __syncthreads();

    const float* seqb = seq + (size_t)b * Tq * D2;

    float pp[Kq][5];
    #pragma unroll
    for (int k = 0; k < Kq; ++k)
        #pragma unroll
        for (int q = 0; q < 5; ++q) pp[k][q] = 0.f;

    for (int s = 0; s < 16; ++s) {
        const int tl = s * 4 + wv;
        const int tt = tc * 64 + tl;
        float prr[Kq];
        #pragma unroll
        for (int k = 0; k < Kq; ++k) prr[k] = pr[tl * Kq + k];
        #pragma unroll
        for (int q = 0; q < 5; ++q) {
            const int d = lane + q * 64;
            const float sv = (d < D2) ? seqb[(size_t)tt * D2 + d] : 0.f;
            #pragma unroll
            for (int k = 0; k < Kq; ++k) pp[k][q] += prr[k] * sv;
        }
    }
    #pragma unroll
    for (int k = 0; k < Kq; ++k)
        #pragma unroll
        for (int q = 0; q < 5; ++q) {
            const int d = lane + q * 64;
            if (d < D2) part[wv][k * D2 + d] = pp[k][q];
        }
    __syncthreads();
    float* op = partial + ((size_t)b * 8 + tc) * (Kq * D2);
    for (int o = tid; o < Kq * D2; o += 256)
        op[o] = part[0][o] + part[1][o] + part[2][o] + part[3][o];
}

// ---------------------------------------------------------------------------
// Kernel 4d: final: pooled reduce -> topic -> logits -> softmax.  grid (B)
// ---------------------------------------------------------------------------
__global__ __launch_bounds__(256) void final_kernel(
    const float* __restrict__ partial,
    const float* __restrict__ Wtop,
    const float* __restrict__ btop,
    const float* __restrict__ Wout,
    const float* __restrict__ bout,
    float* __restrict__ outp)
{
    const int b = blockIdx.x;
    const int tid = threadIdx.x;
    __shared__ float pooled[Kq * D2];
    __shared__ float feats[Kq * THq];
    __shared__ float lsm[8];

    for (int o = tid; o < Kq * D2; o += 256) {
        float s = 0.f;
        #pragma unroll
        for (int c = 0; c < 8; ++c)
            s += partial[((size_t)b * 8 + c) * (Kq * D2) + o];
        pooled[o] = s;
    }
    __syncthreads();

    if (tid < Kq * THq) {
        const int k = tid / THq, hh = tid % THq;
        float acc = btop[tid];
        const float* wp = Wtop + (size_t)k * D2 * THq + hh;
        for (int d = 0; d < D2; ++d)
            acc += pooled[k * D2 + d] * wp[(size_t)d * THq];
        feats[tid] = fmaxf(acc, 0.f);
    }
    __syncthreads();

    if (tid < CLSq) {
        float acc = bout[tid];
        for (int f = 0; f < Kq * THq; ++f)
            acc += feats[f] * Wout[f * CLSq + tid];
        lsm[tid] = acc;
    }
    __syncthreads();
    if (tid < CLSq) {
        float m = lsm[0];
        for (int c = 1; c < CLSq; ++c) m = fmaxf(m, lsm[c]);
        float s = 0.f;
        for (int c = 0; c < CLSq; ++c) s += __expf(lsm[c] - m);
        outp[(size_t)b * CLSq + tid] = __expf(lsm[tid] - m) / s;
    }
}

// ---------------------------------------------------------------------------
// Kernel 5: reg = mean_b regbuf[b]  -> d_out[640]
// ---------------------------------------------------------------------------
__global__ void reg_final(const float* __restrict__ regbuf, float* __restrict__ outp)
{
    const int tid = threadIdx.x;   // 128 threads
    float v = regbuf[tid];
    for (int off = 32; off > 0; off >>= 1) v += __shfl_xor(v, off, 64);
    __shared__ float r2[2];
    if ((tid & 63) == 0) r2[tid >> 6] = v;
    __syncthreads();
    if (tid == 0) outp[Bq * CLSq] = (r2[0] + r2[1]) * (1.f / (float)Bq);
}

// ---------------------------------------------------------------------------
extern "C" void kernel_launch(void* const* d_in, const int* in_sizes, int n_in,
                              void* d_out, int out_size, void* d_ws, size_t ws_size,
                              hipStream_t stream)
{
    const float* x     = (const float*)d_in[0];
    const float* Wih_f = (const float*)d_in[1];
    const float* Whh_f = (const float*)d_in[2];
    const float* bih_f = (const float*)d_in[3];
    const float* bhh_f = (const float*)d_in[4];
    const float* Wih_b = (const float*)d_in[5];
    const float* Whh_b = (const float*)d_in[6];
    const float* bih_b = (const float*)d_in[7];
    const float* bhh_b = (const float*)d_in[8];
    const float* attn_context = (const float*)d_in[9];
    const float* Wattn = (const float*)d_in[10];
    const float* battn = (const float*)d_in[11];
    const float* Wtop  = (const float*)d_in[12];
    const float* btop  = (const float*)d_in[13];
    const float* Wout  = (const float*)d_in[14];
    const float* bout  = (const float*)d_in[15];
    float* outp = (float*)d_out;

    // fixed workspace layout (float units)
    float* ws       = (float*)d_ws;
    float* seqv     = ws;                                   // 19,660,800
    float* hstate   = seqv + (size_t)Bq * Tq * D2;          // 38,400
    float* ctxW     = hstate + (size_t)2 * Bq * Hq;         // 1,800
    float* context  = ctxW + Kq * D2;                       // 230,400
    float* regbuf   = context + (size_t)Bq * Kq * D2;       // 128
    float* normsq   = regbuf + Bq;                          // 768
    float* en       = normsq + Bq * Kq;                     // 393,216
    float* partial  = en + (size_t)Bq * Tq * Kq;            // 1,843,200
    __hip_bfloat16* xb16 = (__hip_bfloat16*)(partial + (size_t)Bq * 8 * Kq * D2); // 19,660,800 bf16
    __hip_bfloat16* Wb16 = xb16 + (size_t)Bq * Tq * Iq;     // 270,000 bf16
    float* gi_chunk = (float*)(Wb16 + (size_t)2 * G3 * Iq); // 115200*TCr fp32
    const size_t fixed_floats = (size_t)(gi_chunk - ws);

    // pick largest TCr in {256,128,64,32} that fits ws_size
    int tcShift = 5;
    for (int sh = 8; sh >= 5; --sh) {
        size_t need = (fixed_floats + (size_t)115200 * (1 << sh)) * 4;
        if (need <= ws_size) { tcShift = sh; break; }
    }
    const int TCr = 1 << tcShift;
    const int NL = Tq / TCr;

    // one-time bf16 casts (x, Wih_f, Wih_b)
    cast_bf16_kernel<<<dim3((Bq * Tq * Iq / 4 + 255) / 256), 256, 0, stream>>>(
        x, xb16, Bq * Tq * Iq / 4);
    cast_bf16_kernel<<<dim3((G3 * Iq / 4 + 255) / 256), 256, 0, stream>>>(
        Wih_f, Wb16, G3 * Iq / 4);
    cast_bf16_kernel<<<dim3((G3 * Iq / 4 + 255) / 256), 256, 0, stream>>>(
        Wih_b, Wb16 + (size_t)G3 * Iq, G3 * Iq / 4);

    for (int c = 0; c < NL; ++c) {
        const int t0f = c * TCr;
        const int t0b = Tq - TCr * (c + 1);
        gi_gemm_mfma<<<dim3(4, Bq * TCr / 128, 2), 256, 0, stream>>>(
            xb16, Wb16, bih_f, bih_b, gi_chunk, t0f, t0b, tcShift);
        gru_rec<<<dim3(2 * Bq), 512, 0, stream>>>(
            gi_chunk, Whh_f, bhh_f, Whh_b, bhh_b, hstate, seqv, c, tcShift);
    }

    ctxw_kernel<<<dim3((Kq * D2 + 255) / 256), 256, 0, stream>>>(
        attn_context, Wattn, battn, ctxW);
    ctx_compute<<<dim3(Bq, Kq), 256, 0, stream>>>(seqv, Wattn, ctxW, context, normsq);
    gram_kernel<<<dim3(Bq), 256, 0, stream>>>(context, normsq, regbuf);
    energy_kernel<<<dim3(8, Bq), 256, 0, stream>>>(seqv, context, en);
    softmax_kernel<<<dim3(Bq), 256, 0, stream>>>(en);
    pooledp_kernel<<<dim3(8, Bq), 256, 0, stream>>>(seqv, en, partial);
    final_kernel<<<dim3(Bq), 256, 0, stream>>>(partial, Wtop, btop, Wout, bout, outp);
    reg_final<<<dim3(1), 128, 0, stream>>>(regbuf, outp);
}